// Round 1
// baseline (361.487 us; speedup 1.0000x reference)
//
#include <hip/hip_runtime.h>
#include <hip/hip_bf16.h>

// SPP patch extraction: feat (512,48,48) fp32 -> for each scale s in
// {4,6,8,10,12,14,16}: sliding s x s windows (stride 2), adaptive max pool
// to 7x7, output (ny*nx, 512*49) per scale, concatenated along patch axis.
//
// One thread per output element; one launch per scale. Writes are fully
// coalesced; input (4.7 MB) is cache-resident so reads come from L2/L3.

#define C_CH 512
#define HW 48
#define POOL 7

__global__ void spp_scale_kernel(const float* __restrict__ feat,
                                 float* __restrict__ out,
                                 int s, int nx, int n_elems) {
    int t = blockIdx.x * blockDim.x + threadIdx.x;
    if (t >= n_elems) return;

    int px = t % POOL;
    int py = (t / POOL) % POOL;
    int c  = (t / (POOL * POOL)) & (C_CH - 1);
    int p  = t / (POOL * POOL * C_CH);
    int ix = p % nx;
    int iy = p / nx;

    int y0 = iy * 2;
    int x0 = ix * 2;

    // torch adaptive_max_pool2d bins: [floor(i*s/7), ceil((i+1)*s/7))
    int ay = (py * s) / POOL;
    int by = ((py + 1) * s + (POOL - 1)) / POOL;
    int ax = (px * s) / POOL;
    int bx = ((px + 1) * s + (POOL - 1)) / POOL;

    const float* chan = feat + (size_t)c * (HW * HW);

    float m = -INFINITY;
    for (int r = ay; r < by; ++r) {
        const float* row = chan + (y0 + r) * HW + x0;
        for (int q = ax; q < bx; ++q) {
            m = fmaxf(m, row[q]);
        }
    }

    out[t] = m;
}

extern "C" void kernel_launch(void* const* d_in, const int* in_sizes, int n_in,
                              void* d_out, int out_size, void* d_ws, size_t ws_size,
                              hipStream_t stream) {
    const float* feat = (const float*)d_in[0];
    float* out = (float*)d_out;

    static const int scales[7] = {4, 6, 8, 10, 12, 14, 16};

    size_t patch_off = 0;  // in units of patches
    for (int i = 0; i < 7; ++i) {
        int s = scales[i];
        int ny = (HW - s) / 2 + 1;
        int nx = ny;
        int n_elems = ny * nx * C_CH * POOL * POOL;
        float* out_s = out + patch_off * (size_t)(C_CH * POOL * POOL);
        int block = 256;
        int grid = (n_elems + block - 1) / block;
        spp_scale_kernel<<<grid, block, 0, stream>>>(feat, out_s, s, nx, n_elems);
        patch_off += (size_t)(ny * nx);
    }
}

// Round 2
// 323.478 us; speedup vs baseline: 1.1175x; 1.1175x over previous
//
#include <hip/hip_runtime.h>
#include <hip/hip_bf16.h>

// SPP patch extraction: feat (512,48,48) fp32 -> for each scale s in
// {4,6,8,10,12,14,16}: sliding s x s windows (stride 2), adaptive max pool
// to 7x7 -> (ny*nx, 512*49) per scale, concatenated along patch axis.
//
// Grid: (98, ny, nx), block 256. blockIdx.y/z carry the patch coords so no
// runtime division anywhere. Scale is a template parameter so bin bounds are
// const-divisor magic ops, and the pooling loops are fixed-trip (maxbin^2),
// fully unrolled, with min()-clamped indices (duplicate reads are harmless
// under max, and clamped indices never leave the valid bin -> no OOB).

#define HW 48
#define POOL 7
#define PATCH_ELEMS (512 * POOL * POOL)  // 25088

constexpr int cdiv7(int x) { return (x + 6) / 7; }

// max adaptive-pool bin size for in=S, out=7
constexpr int max_bin(int S) {
    int m = 0;
    for (int i = 0; i < POOL; ++i) {
        int a = (i * S) / POOL;
        int b = cdiv7((i + 1) * S);
        if (b - a > m) m = b - a;
    }
    return m;
}

template <int S>
__global__ __launch_bounds__(256) void spp_scale_kernel(
    const float* __restrict__ feat, float* __restrict__ out) {
    constexpr int MB = max_bin(S);

    int t = blockIdx.x * 256 + threadIdx.x;       // 0..25087
    int c = t / 49;                               // const-divisor magic
    int k = t - c * 49;
    int py = k / 7;
    int px = k - py * 7;

    int y0 = blockIdx.y * 2;
    int x0 = blockIdx.z * 2;

    int ay = (py * S) / POOL;
    int szy = cdiv7((py + 1) * S) - ay;
    int ax = (px * S) / POOL;
    int szx = cdiv7((px + 1) * S) - ax;

    const float* chan = feat + c * (HW * HW);

    float m = -INFINITY;
#pragma unroll
    for (int r = 0; r < MB; ++r) {
        int rr = y0 + ay + min(r, szy - 1);
        const float* row = chan + rr * HW + x0 + ax;
#pragma unroll
        for (int q = 0; q < MB; ++q) {
            m = fmaxf(m, row[min(q, szx - 1)]);
        }
    }

    size_t patch = (size_t)blockIdx.y * gridDim.z + blockIdx.z;
    out[patch * PATCH_ELEMS + t] = m;
}

template <int S>
static void launch_scale(const float* feat, float* out_s, hipStream_t stream) {
    int ny = (HW - S) / 2 + 1;
    int nx = ny;
    dim3 grid(PATCH_ELEMS / 256, ny, nx);
    spp_scale_kernel<S><<<grid, dim3(256), 0, stream>>>(feat, out_s);
}

extern "C" void kernel_launch(void* const* d_in, const int* in_sizes, int n_in,
                              void* d_out, int out_size, void* d_ws, size_t ws_size,
                              hipStream_t stream) {
    const float* feat = (const float*)d_in[0];
    float* out = (float*)d_out;

    size_t off = 0;  // patches emitted so far
    auto npatch = [](int s) { int n = (HW - s) / 2 + 1; return (size_t)n * n; };

    launch_scale<4>(feat, out + off * PATCH_ELEMS, stream);  off += npatch(4);
    launch_scale<6>(feat, out + off * PATCH_ELEMS, stream);  off += npatch(6);
    launch_scale<8>(feat, out + off * PATCH_ELEMS, stream);  off += npatch(8);
    launch_scale<10>(feat, out + off * PATCH_ELEMS, stream); off += npatch(10);
    launch_scale<12>(feat, out + off * PATCH_ELEMS, stream); off += npatch(12);
    launch_scale<14>(feat, out + off * PATCH_ELEMS, stream); off += npatch(14);
    launch_scale<16>(feat, out + off * PATCH_ELEMS, stream);
}

// Round 3
// 116.336 us; speedup vs baseline: 3.1073x; 2.7806x over previous
//
#include <hip/hip_runtime.h>
#include <hip/hip_bf16.h>

// SPP patch extraction: feat (512,48,48) fp32 -> scales {4,6,8,10,12,14,16},
// sliding SxS windows stride 2, adaptive max pool to 7x7 -> (ny*nx, 512*49),
// concatenated over scales.
//
// R3: fix load-address divergence (R2 was ~330us, load-path bound).
// Block = (channel chunk of 32, iy, ix). Coalesced float2 staging of the
// 32xSxS window into LDS; separable row-then-col max with statically indexed
// register rowmax (LDS reads merge to b64/b128); outputs staged in LDS and
// written out as coalesced float2.

#define HW 48
#define CHAN_STRIDE (HW * HW)  // 2304
#define POOL 7
#define PATCH_ELEMS (512 * POOL * POOL)  // 25088
#define CH 32                            // channels per block

constexpr int cdiv7(int x) { return (x + 6) / 7; }

constexpr int max_bin(int S) {
    int m = 0;
    for (int i = 0; i < POOL; ++i) {
        int a = (i * S) / POOL;
        int b = cdiv7((i + 1) * S);
        if (b - a > m) m = b - a;
    }
    return m;
}

template <int S>
__global__ __launch_bounds__(256) void spp_scale_kernel(
    const float* __restrict__ feat, float* __restrict__ out) {
    constexpr int SS = S * S;
    constexpr int E2 = CH * SS / 2;      // float2 elements to stage
    constexpr int MBY = max_bin(S);

    __shared__ __align__(16) float win[CH * SS];
    __shared__ __align__(16) float outb[CH * POOL * POOL];

    const int chunk = blockIdx.x;
    const int y0 = blockIdx.y * 2;
    const int x0 = blockIdx.z * 2;
    const int c0 = chunk * CH;
    const float* base = feat + (size_t)c0 * CHAN_STRIDE;

    // ---- stage window: coalesced float2 loads, linear LDS ----
#pragma unroll
    for (int i = 0; i < (E2 + 255) / 256; ++i) {
        int l2 = threadIdx.x + i * 256;
        if ((E2 % 256 == 0) || (l2 < E2)) {
            int c = l2 / (SS / 2);
            int rem = l2 - c * (SS / 2);
            int row = rem / (S / 2);
            int col2 = rem - row * (S / 2);
            float2 v = *(const float2*)(base + c * CHAN_STRIDE +
                                        (y0 + row) * HW + x0 + 2 * col2);
            *(float2*)(&win[l2 * 2]) = v;
        }
    }
    __syncthreads();

    // ---- separable pooling: task = (c_local, py) ----
    if (threadIdx.x < CH * POOL) {
        int c = threadIdx.x / POOL;
        int py = threadIdx.x - c * POOL;
        int ay = (py * S) / POOL;
        int szy = cdiv7((py + 1) * S) - ay;

        float rm[S];
#pragma unroll
        for (int x = 0; x < S; ++x) rm[x] = -INFINITY;
#pragma unroll
        for (int r = 0; r < MBY; ++r) {
            int rr = ay + min(r, szy - 1);           // clamped dup rows: ok under max
            const float* rowp = &win[c * SS + rr * S];
#pragma unroll
            for (int x = 0; x < S; ++x) rm[x] = fmaxf(rm[x], rowp[x]);
        }

        float* ob = &outb[c * 49 + py * POOL];
#pragma unroll
        for (int px = 0; px < POOL; ++px) {
            int ax = (px * S) / POOL;                // compile-time (px unrolled)
            int bx = cdiv7((px + 1) * S);
            float m = rm[ax];
#pragma unroll
            for (int q = 1; q < max_bin(S); ++q)
                if (ax + q < bx) m = fmaxf(m, rm[ax + q]);
            ob[px] = m;
        }
    }
    __syncthreads();

    // ---- coalesced copy-out ----
    size_t patch = (size_t)blockIdx.y * gridDim.z + blockIdx.z;
    float* obase = out + patch * PATCH_ELEMS + (size_t)c0 * 49;
    const float2* src = (const float2*)outb;
    float2* dst = (float2*)obase;
#pragma unroll
    for (int i = threadIdx.x; i < CH * 49 / 2; i += 256) dst[i] = src[i];
}

template <int S>
static void launch_scale(const float* feat, float* out_s, hipStream_t stream) {
    int ny = (HW - S) / 2 + 1;
    dim3 grid(512 / CH, ny, ny);
    spp_scale_kernel<S><<<grid, dim3(256), 0, stream>>>(feat, out_s);
}

extern "C" void kernel_launch(void* const* d_in, const int* in_sizes, int n_in,
                              void* d_out, int out_size, void* d_ws, size_t ws_size,
                              hipStream_t stream) {
    const float* feat = (const float*)d_in[0];
    float* out = (float*)d_out;

    size_t off = 0;  // patches emitted so far
    auto npatch = [](int s) { int n = (HW - s) / 2 + 1; return (size_t)n * n; };

    launch_scale<4>(feat, out + off * PATCH_ELEMS, stream);  off += npatch(4);
    launch_scale<6>(feat, out + off * PATCH_ELEMS, stream);  off += npatch(6);
    launch_scale<8>(feat, out + off * PATCH_ELEMS, stream);  off += npatch(8);
    launch_scale<10>(feat, out + off * PATCH_ELEMS, stream); off += npatch(10);
    launch_scale<12>(feat, out + off * PATCH_ELEMS, stream); off += npatch(12);
    launch_scale<14>(feat, out + off * PATCH_ELEMS, stream); off += npatch(14);
    launch_scale<16>(feat, out + off * PATCH_ELEMS, stream);
}

// Round 5
// 87.133 us; speedup vs baseline: 4.1487x; 1.3352x over previous
//
#include <hip/hip_runtime.h>
#include <hip/hip_bf16.h>

// SPP patch extraction, fused single-launch version.
// feat (512,48,48) fp32; scales {4,6,8,10,12,14,16}, stride-2 SxS windows,
// adaptive max pool to 7x7 -> (ny*nx, 512*49) per scale, concatenated.
//
// Block = (scale, 8-channel chunk, iy): stages 8ch x S x 48 row-strip
// (contiguous float4 copy), computes shared y-binned row max rp[c][py][x]
// once, then emits all nx patches of that row directly to global (each
// patch's 392-float chunk is contiguous -> coalesced).
//
// R5 fix: LUT szx field widened to 3 bits (max_bin(16)=4 overflowed 2 bits
// in R4 -> scale-16 outputs wrong).

#define HW 48
#define CSTR (HW * HW)   // 2304
#define POOL 7
#define PE 25088         // 512*49 elems per patch
#define CH 8             // channels per block
#define CHUNKS 64        // 512/CH

constexpr int cdiv7(int x) { return (x + 6) / 7; }
constexpr int nyf(int S) { return (HW - S) / 2 + 1; }
constexpr int max_bin(int S) {
    int m = 0;
    for (int i = 0; i < POOL; ++i) {
        int a = (i * S) / POOL, b = cdiv7((i + 1) * S);
        if (b - a > m) m = b - a;
    }
    return m;
}

template <int S>
__device__ __forceinline__ void run_scale(int b, const float* __restrict__ feat,
                                          float* __restrict__ outp,
                                          float* win, float* rp, int* lut) {
    constexpr int NX = nyf(S);
    constexpr int MB = max_bin(S);
    const int tid = threadIdx.x;
    const int iy = b >> 6;       // CHUNKS == 64
    const int chunk = b & 63;
    const int c0 = chunk * CH;
    const int y0 = iy * 2;

    // ---- stage: CH channels x (S rows x 48 cols), contiguous per channel ----
    constexpr int E4 = CH * S * 12;  // float4 count
    const float* fb = feat + (size_t)c0 * CSTR + y0 * HW;
    for (int l = tid; l < E4; l += 256) {
        int c = l / (S * 12);
        int rem = l - c * (S * 12);
        ((float4*)win)[l] = ((const float4*)(fb + c * CSTR))[rem];
    }

    // ---- LUT over j in [0,392): row=(c*7+py), ax (5b), szx (3b) ----
    for (int j = tid; j < CH * 49; j += 256) {
        int c = j / 49, jj = j - 49 * c;
        int py = jj / 7, px = jj - 7 * py;
        int ax = (px * S) / POOL;
        int szx = cdiv7((px + 1) * S) - ax;
        lut[j] = ((c * 7 + py) << 8) | (ax << 3) | szx;
    }
    __syncthreads();

    // ---- y-reduce: rp[c*7+py][x] = max over y-bin, x = 0..47 ----
    for (int t = tid; t < CH * POOL * HW; t += 256) {
        int c = t / (POOL * HW);
        int rem = t - c * (POOL * HW);
        int py = rem / HW;
        int x = rem - py * HW;
        int ay = (py * S) / POOL;
        int szy = cdiv7((py + 1) * S) - ay;
        const float* wb = win + c * (S * HW) + ay * HW + x;
        float m = wb[0];
#pragma unroll
        for (int r = 1; r < MB; ++r)
            m = fmaxf(m, wb[min(r, szy - 1) * HW]);   // clamped dup rows ok
        rp[(c * POOL + py) * 50 + x] = m;
    }
    __syncthreads();

    // ---- outputs: all nx patches of this row ----
    constexpr int TOT = NX * CH * 49;
    for (int k = tid; k < TOT; k += 256) {
        int ix = k / 392;
        int j = k - 392 * ix;
        int e = lut[j];
        int row = e >> 8;
        int ax = (e >> 3) & 31;
        int szx = e & 7;
        const float* rb = rp + row * 50 + 2 * ix + ax;
        float m = rb[0];
#pragma unroll
        for (int q = 1; q < MB; ++q)
            m = fmaxf(m, rb[min(q, szx - 1)]);
        outp[(size_t)(iy * NX + ix) * PE + c0 * 49 + j] = m;
    }
}

__global__ __launch_bounds__(256) void spp_fused(const float* __restrict__ feat,
                                                 float* __restrict__ out) {
    __shared__ __align__(16) float win[CH * 16 * HW];  // 24 KB (max S=16)
    __shared__ float rp[CH * POOL * 50];               // 11.2 KB
    __shared__ int lut[CH * 49];                       // 1.6 KB
    int b = blockIdx.x;
    // block bases: 64*ny per scale; patch offsets cumulative.
    if (b < 1472)      run_scale<4>(b,        feat, out,                      win, rp, lut);
    else if (b < 2880) run_scale<6>(b - 1472, feat, out + (size_t)529  * PE, win, rp, lut);
    else if (b < 4224) run_scale<8>(b - 2880, feat, out + (size_t)1013 * PE, win, rp, lut);
    else if (b < 5504) run_scale<10>(b - 4224, feat, out + (size_t)1454 * PE, win, rp, lut);
    else if (b < 6720) run_scale<12>(b - 5504, feat, out + (size_t)1854 * PE, win, rp, lut);
    else if (b < 7872) run_scale<14>(b - 6720, feat, out + (size_t)2215 * PE, win, rp, lut);
    else               run_scale<16>(b - 7872, feat, out + (size_t)2539 * PE, win, rp, lut);
}

extern "C" void kernel_launch(void* const* d_in, const int* in_sizes, int n_in,
                              void* d_out, int out_size, void* d_ws, size_t ws_size,
                              hipStream_t stream) {
    const float* feat = (const float*)d_in[0];
    float* out = (float*)d_out;
    spp_fused<<<8960, 256, 0, stream>>>(feat, out);
}

// Round 6
// 72.060 us; speedup vs baseline: 5.0165x; 1.2092x over previous
//
#include <hip/hip_runtime.h>
#include <hip/hip_bf16.h>

// SPP patch extraction, fused single-launch.
// feat (512,48,48) fp32; scales {4,6,8,10,12,14,16}, stride-2 SxS windows,
// adaptive max pool 7x7 -> (ny*nx, 512*49) per scale, concatenated.
//
// Block = (scale, 8-channel chunk, iy). Phases:
//  1. stage 8ch x S x 48 row-strip (float4 coalesced) -> win
//  2. y-reduce: rp[row=c*7+py][x] = max over y-bin (shared by all nx patches)
//  3. x-pool: thread = (row, ix) reads rp[row][2ix..2ix+S) as float2s,
//     computes all 7 px bins with COMPILE-TIME ax/bx (px unrolled, no LUT),
//     writes 7 floats to outb in final output order. outb overlays win.
//  4. copy-out: float4 LDS reads -> global_store_dwordx4 (coalesced).

#define HW 48
#define CSTR (HW * HW)   // 2304
#define POOL 7
#define PE 25088         // 512*49 elems per patch
#define CH 8             // channels per block
#define RPS 50           // rp row stride (floats), even (float2 align)

constexpr int cdiv7(int x) { return (x + 6) / 7; }
constexpr int nyf(int S) { return (HW - S) / 2 + 1; }
constexpr int max_bin(int S) {
    int m = 0;
    for (int i = 0; i < POOL; ++i) {
        int a = (i * S) / POOL, b = cdiv7((i + 1) * S);
        if (b - a > m) m = b - a;
    }
    return m;
}

template <int S>
__device__ __forceinline__ void run_scale(int b, const float* __restrict__ feat,
                                          float* __restrict__ outp,
                                          float* smain, float* rp) {
    constexpr int NX = nyf(S);
    constexpr int MB = max_bin(S);
    const int tid = threadIdx.x;
    const int iy = b >> 6;           // 64 chunks
    const int c0 = (b & 63) * CH;
    const int y0 = iy * 2;

    float* win = smain;              // phase 1-2
    float* outb = smain;             // phase 3-4 (overlays win)

    // ---- 1. stage: CH channels x S rows x 48 cols, contiguous per channel ----
    constexpr int E4 = CH * S * 12;  // float4 count
    const float* fb = feat + (size_t)c0 * CSTR + y0 * HW;
    for (int l = tid; l < E4; l += 256) {
        int c = l / (S * 12);
        int rem = l - c * (S * 12);
        ((float4*)win)[l] = ((const float4*)(fb + c * CSTR))[rem];
    }
    __syncthreads();

    // ---- 2. y-reduce: rp[row][x], row = c*7+py ----
    for (int t = tid; t < CH * POOL * HW; t += 256) {
        int c = t / (POOL * HW);
        int rem = t - c * (POOL * HW);
        int py = rem / HW;
        int x = rem - py * HW;
        int ay = (py * S) / POOL;
        int szy = cdiv7((py + 1) * S) - ay;
        const float* wb = win + c * (S * HW) + ay * HW + x;
        float m = wb[0];
#pragma unroll
        for (int r = 1; r < MB; ++r)
            m = fmaxf(m, wb[min(r, szy - 1) * HW]);  // clamped dup rows ok
        rp[(c * POOL + py) * RPS + x] = m;
    }
    __syncthreads();

    // ---- 3. x-pool: thread = (row, ix); all indices compile-time ----
    constexpr int T3 = CH * POOL * NX;
    for (int t = tid; t < T3; t += 256) {
        int row = t / NX;            // const-divisor magic
        int ix = t - row * NX;
        const float* v = rp + row * RPS + 2 * ix;   // 8B-aligned
        float x[S];
#pragma unroll
        for (int k = 0; k < S / 2; ++k) {
            float2 p = *(const float2*)(v + 2 * k);
            x[2 * k] = p.x;
            x[2 * k + 1] = p.y;
        }
        float* ob = outb + ix * 392 + row * 7;      // final output order
#pragma unroll
        for (int px = 0; px < POOL; ++px) {
            int ax = (px * S) / POOL;               // compile-time
            int bx = cdiv7((px + 1) * S);
            float m = x[ax];
#pragma unroll
            for (int k = ax + 1; k < bx; ++k) m = fmaxf(m, x[k]);
            ob[px] = m;
        }
    }
    __syncthreads();

    // ---- 4. copy-out: NX*392 floats, float4 both sides ----
    constexpr int C4 = NX * 98;      // 392/4 per patch
    float* obase = outp + (size_t)iy * NX * PE + (size_t)c0 * 49;
    for (int k = tid; k < C4; k += 256) {
        int ix = k / 98;             // const-divisor magic
        int m4 = k - ix * 98;
        float4 vv = ((const float4*)outb)[k];
        *(float4*)(obase + (size_t)ix * PE + m4 * 4) = vv;
    }
}

__global__ __launch_bounds__(256) void spp_fused(const float* __restrict__ feat,
                                                 float* __restrict__ out) {
    // smain = max over scales of max(win, outb) floats:
    //   win = CH*S*48 (max 6144 @S=16); outb = NX*392 (max 9016 @S=4)
    __shared__ __align__(16) float smain[9016];      // 36.1 KB
    __shared__ __align__(16) float rp[CH * POOL * RPS];  // 11.2 KB
    int b = blockIdx.x;
    if (b < 1472)      run_scale<4>(b,         feat, out,                      smain, rp);
    else if (b < 2880) run_scale<6>(b - 1472,  feat, out + (size_t)529  * PE, smain, rp);
    else if (b < 4224) run_scale<8>(b - 2880,  feat, out + (size_t)1013 * PE, smain, rp);
    else if (b < 5504) run_scale<10>(b - 4224, feat, out + (size_t)1454 * PE, smain, rp);
    else if (b < 6720) run_scale<12>(b - 5504, feat, out + (size_t)1854 * PE, smain, rp);
    else if (b < 7872) run_scale<14>(b - 6720, feat, out + (size_t)2215 * PE, smain, rp);
    else               run_scale<16>(b - 7872, feat, out + (size_t)2539 * PE, smain, rp);
}

extern "C" void kernel_launch(void* const* d_in, const int* in_sizes, int n_in,
                              void* d_out, int out_size, void* d_ws, size_t ws_size,
                              hipStream_t stream) {
    const float* feat = (const float*)d_in[0];
    float* out = (float*)d_out;
    spp_fused<<<8960, 256, 0, stream>>>(feat, out);
}

// Round 7
// 67.584 us; speedup vs baseline: 5.3487x; 1.0662x over previous
//
#include <hip/hip_runtime.h>
#include <hip/hip_bf16.h>

// SPP patch extraction, fused single-launch.
// feat (512,48,48) fp32; scales {4,6,8,10,12,14,16}, stride-2 SxS windows,
// adaptive max pool 7x7 -> (ny*nx, 512*49) per scale, concatenated.
//
// R7: maximize store-pipe overlap.
//  - No win staging: y-reduce reads feat direct from L1/L2 (input is
//    cache-resident; per-wave addresses are 48-float contiguous runs).
//  - rp[row=c*7+py][x]: y-binned max, computed once per (chunk,iy) block.
//  - Emit tiled over ix in chunks of NXT=8 patches, DOUBLE-BUFFERED outb:
//    per tile iteration: issue stores of previous tile (P4) first, then
//    compute current tile (P3), then one barrier -> stores drain under the
//    next tile's compute. LDS 36.3 KB -> 4 blocks/CU.

#define HW 48
#define CSTR (HW * HW)   // 2304
#define POOL 7
#define PE 25088         // 512*49 elems per patch
#define CH 8             // channels per block
#define RPS 50           // rp row stride (floats)
#define NXT 8            // patches per emit tile

constexpr int cdiv7(int x) { return (x + 6) / 7; }
constexpr int nyf(int S) { return (HW - S) / 2 + 1; }
constexpr int max_bin(int S) {
    int m = 0;
    for (int i = 0; i < POOL; ++i) {
        int a = (i * S) / POOL, b = cdiv7((i + 1) * S);
        if (b - a > m) m = b - a;
    }
    return m;
}

template <int S>
__device__ __forceinline__ void run_scale(int b, const float* __restrict__ feat,
                                          float* __restrict__ outp,
                                          float* rp, float* ba, float* bb) {
    constexpr int NX = nyf(S);
    constexpr int MB = max_bin(S);
    constexpr int NT = (NX + NXT - 1) / NXT;
    const int tid = threadIdx.x;
    const int iy = b >> 6;           // 64 chunks
    const int c0 = (b & 63) * CH;
    const int y0 = iy * 2;

    // ---- P2: rp[row][x] = y-binned max, direct from global ----
    const float* fb = feat + (size_t)c0 * CSTR + y0 * HW;
    for (int t = tid; t < CH * POOL * HW; t += 256) {
        int c = t / (POOL * HW);
        int rem = t - c * (POOL * HW);
        int py = rem / HW;
        int x = rem - py * HW;
        int ay = (py * S) / POOL;
        int szy = cdiv7((py + 1) * S) - ay;
        const float* wb = fb + c * CSTR + ay * HW + x;
        float m = wb[0];
#pragma unroll
        for (int r = 1; r < MB; ++r)
            m = fmaxf(m, wb[min(r, szy - 1) * HW]);  // clamped dup rows ok
        rp[(c * POOL + py) * RPS + x] = m;
    }

    float* obase = outp + (size_t)iy * NX * PE + (size_t)c0 * 49;

    // P3: compute tile t into buf (ragged tail handled by clamping ix)
    auto p3 = [&](float* buf, int t0) {
        int ix0 = t0 * NXT;
        for (int t = tid; t < CH * POOL * NXT; t += 256) {   // 448
            int row = t >> 3;
            int ixl = t & 7;
            int ixg = min(ix0 + ixl, NX - 1);
            const float* v = rp + row * RPS + 2 * ixg;       // 8B-aligned
            float x[S];
#pragma unroll
            for (int k = 0; k < S / 2; ++k) {
                float2 p = *(const float2*)(v + 2 * k);
                x[2 * k] = p.x;
                x[2 * k + 1] = p.y;
            }
            float* ob = buf + ixl * 392 + row * 7;           // output order
#pragma unroll
            for (int px = 0; px < POOL; ++px) {
                int ax = (px * S) / POOL;                    // compile-time
                int bx = cdiv7((px + 1) * S);
                float m = x[ax];
#pragma unroll
                for (int k = ax + 1; k < bx; ++k) m = fmaxf(m, x[k]);
                ob[px] = m;
            }
        }
    };

    // P4: store tile t (float4 LDS reads -> dwordx4 coalesced stores)
    auto p4 = [&](const float* buf, int t0) {
        int ix0 = t0 * NXT;
        int w = min(NXT, NX - ix0);
        for (int k = tid; k < w * 98; k += 256) {
            int ix = k / 98;                                 // magic const
            int m4 = k - ix * 98;
            float4 vv = ((const float4*)buf)[k];
            *(float4*)(obase + (size_t)(ix0 + ix) * PE + m4 * 4) = vv;
        }
    };

    __syncthreads();          // rp ready
    p3(ba, 0);
    __syncthreads();
    float* cur = ba;
    float* nxt = bb;
    for (int t = 1; t < NT; ++t) {
        p4(cur, t - 1);       // issue stores first: drain under p3 below
        p3(nxt, t);
        __syncthreads();
        float* tmp = cur; cur = nxt; nxt = tmp;
    }
    p4(cur, NT - 1);
}

__global__ __launch_bounds__(256) void spp_fused(const float* __restrict__ feat,
                                                 float* __restrict__ out) {
    __shared__ float rp[CH * POOL * RPS];                // 11.2 KB
    __shared__ __align__(16) float ba[NXT * 392];        // 12.5 KB
    __shared__ __align__(16) float bb[NXT * 392];        // 12.5 KB
    int b = blockIdx.x;
    if (b < 1472)      run_scale<4>(b,         feat, out,                     rp, ba, bb);
    else if (b < 2880) run_scale<6>(b - 1472,  feat, out + (size_t)529  * PE, rp, ba, bb);
    else if (b < 4224) run_scale<8>(b - 2880,  feat, out + (size_t)1013 * PE, rp, ba, bb);
    else if (b < 5504) run_scale<10>(b - 4224, feat, out + (size_t)1454 * PE, rp, ba, bb);
    else if (b < 6720) run_scale<12>(b - 5504, feat, out + (size_t)1854 * PE, rp, ba, bb);
    else if (b < 7872) run_scale<14>(b - 6720, feat, out + (size_t)2215 * PE, rp, ba, bb);
    else               run_scale<16>(b - 7872, feat, out + (size_t)2539 * PE, rp, ba, bb);
}

extern "C" void kernel_launch(void* const* d_in, const int* in_sizes, int n_in,
                              void* d_out, int out_size, void* d_ws, size_t ws_size,
                              hipStream_t stream) {
    const float* feat = (const float*)d_in[0];
    float* out = (float*)d_out;
    spp_fused<<<8960, 256, 0, stream>>>(feat, out);
}